// Round 2
// baseline (90.629 us; speedup 1.0000x reference)
//
#include <hip/hip_runtime.h>
#include <math.h>

// Black-oil Peaceman well loss.
// X: (4096, 89, 128) f32;  Y: (4096, 66, 128) f32;  out: (4096, 66, 128) f32.

#define N_BATCH   4096
#define XC        89
#define YC        66
#define S         128
#define PI_F      3.14159265358979323846f
#define LN2_F     0.6931471805599453f

// ---------------- kernel 1: per-n scalars (4 waves / block) ----------------
__global__ void __launch_bounds__(256) pmean_kernel(const float* __restrict__ X,
                                                    float* __restrict__ coef) {
    const int wave = threadIdx.x >> 6;               // 0..3
    const int lane = threadIdx.x & 63;
    const int n    = blockIdx.x * 4 + wave;
    const float* row = X + (size_t)n * (XC * S) + 22 * S;
    float2 v = *reinterpret_cast<const float2*>(row + lane * 2);
    float sum = v.x + v.y;
    #pragma unroll
    for (int off = 32; off > 0; off >>= 1)
        sum += __shfl_down(sum, off, 64);
    if (lane == 0) {
        const float p  = sum * (1.0f / (float)S);
        const float dd = p - 100.0f;                 // drawdown (negative)
        const bool  lt = (p < 0.5f);                 // p < P_BUB
        const float dp = lt ? (0.1f - p) : (0.1f - 0.5f);
        const float bg = expf(-0.0017f * dp);
        const float e1 = lt ? (-8e-5f * (0.1f - p)) : (-8e-5f * (0.1f - 0.5f));
        const float e2 = -1e-5f * (lt ? 0.0f : (p - 0.5f));
        const float bo = expf(-(e1 + e2));
        const float mug = 3e-10f * p * p + 1e-6f * p + 0.0133f;
        const float base = 2.0f * PI_F * 100.0f / LN2_F;   // 2*pi*DZ / ln(RE/RWELL)
        const float add  = fabsf(dd) * base;
        float4 c;
        c.x = add / (2.5f * bo);        // oil:   UO * bo
        c.y = add;                      // water: UW * BW = 1
        c.z = add / (mug * bg);         // gas
        c.w = 0.0f;
        *reinterpret_cast<float4*>(coef + n * 4) = c;
    }
}

// ---------------- kernel 2: streaming elementwise, 8 floats/thread/stream ----
#define COMP(v, j) ((&(v).x)[j])

__global__ void __launch_bounds__(256) blackoil_kernel(const float* __restrict__ X,
                                                       const float* __restrict__ Y,
                                                       const float* __restrict__ coef,
                                                       float* __restrict__ out) {
    const int tid = blockIdx.x * 256 + threadIdx.x;
    const int s8  = tid & 15;          // which group of 8 s-values
    const int row = tid >> 4;          // n*22 + k
    const int k   = row % 22;
    const int n   = row / 22;

    const float* xb = X   + (size_t)n * (XC * S);
    const float* yb = Y   + (size_t)n * (YC * S);
    float*       ob = out + (size_t)n * (YC * S);
    const int so = s8 * 8;

    // 12 loads issued back-to-back for MLP
    const float4 perm0 = *reinterpret_cast<const float4*>(xb + k * S + so);
    const float4 perm1 = *reinterpret_cast<const float4*>(xb + k * S + so + 4);
    const float4 sg0   = *reinterpret_cast<const float4*>(xb + (45 + k) * S + so);
    const float4 sg1   = *reinterpret_cast<const float4*>(xb + (45 + k) * S + so + 4);
    const float4 sw0   = *reinterpret_cast<const float4*>(xb + (67 + k) * S + so);
    const float4 sw1   = *reinterpret_cast<const float4*>(xb + (67 + k) * S + so + 4);
    const float4 r_o0  = *reinterpret_cast<const float4*>(yb + k * S + so);
    const float4 r_o1  = *reinterpret_cast<const float4*>(yb + k * S + so + 4);
    const float4 r_w0  = *reinterpret_cast<const float4*>(yb + (22 + k) * S + so);
    const float4 r_w1  = *reinterpret_cast<const float4*>(yb + (22 + k) * S + so + 4);
    const float4 r_g0  = *reinterpret_cast<const float4*>(yb + (44 + k) * S + so);
    const float4 r_g1  = *reinterpret_cast<const float4*>(yb + (44 + k) * S + so + 4);
    const float4 c     = *reinterpret_cast<const float4*>(coef + n * 4);

    const float inv_denom = 1.0f / 0.7f;            // 1/(1-SWI-SOR)
    const float scale     = 1e-10f / (float)N_BATCH;

    float4 o_o0, o_w0, o_g0, o_o1, o_w1, o_g1;
    #pragma unroll
    for (int j = 0; j < 4; ++j) {
        {
            const float swn = (COMP(sw0, j) - 0.1f) * inv_denom;
            const float sgn = COMP(sg0, j) * inv_denom;
            const float krw = 0.3f * swn * swn;
            const float aa  = 1.0f - swn;
            const float bb  = 1.0f - sgn;
            const float kro = 0.9f * (aa * aa) * (bb * bb);
            const float krg = 0.8f * sgn * sgn;
            const float pk  = COMP(perm0, j);
            COMP(o_o0, j) = (fabsf(c.x * pk * kro) - COMP(r_o0, j)) * scale;
            COMP(o_w0, j) = (fabsf(c.y * pk * krw) - COMP(r_w0, j)) * scale;
            COMP(o_g0, j) = (fabsf(c.z * pk * krg) - COMP(r_g0, j)) * scale;
        }
        {
            const float swn = (COMP(sw1, j) - 0.1f) * inv_denom;
            const float sgn = COMP(sg1, j) * inv_denom;
            const float krw = 0.3f * swn * swn;
            const float aa  = 1.0f - swn;
            const float bb  = 1.0f - sgn;
            const float kro = 0.9f * (aa * aa) * (bb * bb);
            const float krg = 0.8f * sgn * sgn;
            const float pk  = COMP(perm1, j);
            COMP(o_o1, j) = (fabsf(c.x * pk * kro) - COMP(r_o1, j)) * scale;
            COMP(o_w1, j) = (fabsf(c.y * pk * krw) - COMP(r_w1, j)) * scale;
            COMP(o_g1, j) = (fabsf(c.z * pk * krg) - COMP(r_g1, j)) * scale;
        }
    }

    *reinterpret_cast<float4*>(ob + k * S + so)            = o_o0;
    *reinterpret_cast<float4*>(ob + k * S + so + 4)        = o_o1;
    *reinterpret_cast<float4*>(ob + (22 + k) * S + so)     = o_w0;
    *reinterpret_cast<float4*>(ob + (22 + k) * S + so + 4) = o_w1;
    *reinterpret_cast<float4*>(ob + (44 + k) * S + so)     = o_g0;
    *reinterpret_cast<float4*>(ob + (44 + k) * S + so + 4) = o_g1;
}

extern "C" void kernel_launch(void* const* d_in, const int* in_sizes, int n_in,
                              void* d_out, int out_size, void* d_ws, size_t ws_size,
                              hipStream_t stream) {
    const float* X = (const float*)d_in[0];
    const float* Y = (const float*)d_in[1];
    float* out  = (float*)d_out;
    float* coef = (float*)d_ws;                 // 4096 * 4 floats = 64 KB

    pmean_kernel<<<N_BATCH / 4, 256, 0, stream>>>(X, coef);

    const int total  = N_BATCH * 22 * (S / 8);  // threads
    const int blocks = total / 256;             // exact: 5632
    blackoil_kernel<<<blocks, 256, 0, stream>>>(X, Y, coef, out);
}

// Round 3
// 83.941 us; speedup vs baseline: 1.0797x; 1.0797x over previous
//
#include <hip/hip_runtime.h>
#include <math.h>

// Black-oil Peaceman well loss — fully fused, one block per batch element n.
// X: (4096, 89, 128) f32;  Y: (4096, 66, 128) f32;  out: (4096, 66, 128) f32.
//
// Per n: p_mean = mean(X[n,22,:]) -> 3 scalar coefficients; then elementwise
// over 22 channels x 128 samples:
//   out[n, k     ,s] = (|dd|*B/(UO*bo)  * perm*kro - Y[n,k     ,s]) * 1e-10/N
//   out[n, 22+k  ,s] = (|dd|*B          * perm*krw - Y[n,22+k  ,s]) * 1e-10/N
//   out[n, 44+k  ,s] = (|dd|*B/(mug*bg) * perm*krg - Y[n,44+k  ,s]) * 1e-10/N
// B = 2*pi*DZ/ln(RE/RWELL) = 200*pi/ln2.

#define N_BATCH   4096
#define PI_F      3.14159265358979323846f
#define LN2_F     0.6931471805599453f
#define COMP(v, j) ((&(v).x)[j])

__global__ void __launch_bounds__(256) blackoil_fused(const float* __restrict__ X,
                                                      const float* __restrict__ Y,
                                                      float* __restrict__ out) {
    const int n = blockIdx.x;
    const int t = threadIdx.x;
    const float* xb = X   + (size_t)n * (89 * 128);
    const float* yb = Y   + (size_t)n * (66 * 128);
    float*       ob = out + (size_t)n * (66 * 128);

    __shared__ float sc[3];

    // ---- per-n scalars: mean of pressure row (wave 0 only) ----
    if (t < 64) {
        float2 v = *reinterpret_cast<const float2*>(xb + 22 * 128 + t * 2);
        float sum = v.x + v.y;
        #pragma unroll
        for (int off = 32; off > 0; off >>= 1)
            sum += __shfl_down(sum, off, 64);
        if (t == 0) {
            const float p  = sum * (1.0f / 128.0f);
            const float dd = p - 100.0f;                  // drawdown (negative)
            const bool  lt = (p < 0.5f);                  // p < P_BUB
            const float dp = lt ? (0.1f - p) : -0.4f;     // calc_dp
            const float bg = expf(-0.0017f * dp);         // calc_bg
            const float e1 = -8e-5f * dp;
            const float e2 = -1e-5f * (lt ? 0.0f : (p - 0.5f));
            const float bo = expf(-(e1 + e2));            // calc_bo
            const float mug = 3e-10f * p * p + 1e-6f * p + 0.0133f;
            const float add = fabsf(dd) * (2.0f * PI_F * 100.0f / LN2_F);
            sc[0] = add / (2.5f * bo);                    // oil
            sc[1] = add;                                  // water (UW*BW = 1)
            sc[2] = add / (mug * bg);                     // gas
        }
    }
    __syncthreads();
    const float cx = sc[0], cy = sc[1], cz = sc[2];

    // ---- streaming elementwise over this n's 22x128 region ----
    const float inv_denom = 1.0f / 0.7f;                  // 1/(1-SWI-SOR)
    const float scale     = 1e-10f / (float)N_BATCH;

    const float4* x4 = reinterpret_cast<const float4*>(xb);
    const float4* y4 = reinterpret_cast<const float4*>(yb);
    float4*       o4 = reinterpret_cast<float4*>(ob);

    // float4-region offsets: perm @0, Sg @45*32=1440, Sw @67*32=2144 (X);
    // oil @0, water @704, gas @1408 (Y and out). 22*32 = 704 float4s total.
    #pragma unroll
    for (int i = 0; i < 3; ++i) {
        const int idx = t + i * 256;
        if (idx < 704) {
            const float4 perm = x4[idx];
            const float4 sg   = x4[1440 + idx];
            const float4 sw   = x4[2144 + idx];
            const float4 r_o  = y4[idx];
            const float4 r_w  = y4[704 + idx];
            const float4 r_g  = y4[1408 + idx];

            float4 oo, ow, og;
            #pragma unroll
            for (int j = 0; j < 4; ++j) {
                const float swn = (COMP(sw, j) - 0.1f) * inv_denom;
                const float sgn = COMP(sg, j) * inv_denom;
                const float krw = 0.3f * swn * swn;
                const float aa  = 1.0f - swn;
                const float bb  = 1.0f - sgn;
                const float kro = 0.9f * (aa * aa) * (bb * bb);
                const float krg = 0.8f * sgn * sgn;
                const float pk  = COMP(perm, j);
                COMP(oo, j) = (fabsf(cx * pk * kro) - COMP(r_o, j)) * scale;
                COMP(ow, j) = (fabsf(cy * pk * krw) - COMP(r_w, j)) * scale;
                COMP(og, j) = (fabsf(cz * pk * krg) - COMP(r_g, j)) * scale;
            }
            o4[idx]        = oo;
            o4[704 + idx]  = ow;
            o4[1408 + idx] = og;
        }
    }
}

extern "C" void kernel_launch(void* const* d_in, const int* in_sizes, int n_in,
                              void* d_out, int out_size, void* d_ws, size_t ws_size,
                              hipStream_t stream) {
    const float* X = (const float*)d_in[0];
    const float* Y = (const float*)d_in[1];
    float* out = (float*)d_out;
    blackoil_fused<<<N_BATCH, 256, 0, stream>>>(X, Y, out);
}

// Round 5
// 64.875 us; speedup vs baseline: 1.3970x; 1.2939x over previous
//
#include <hip/hip_runtime.h>
#include <math.h>

// Black-oil Peaceman well loss — fused, barrier-free, one block per n.
// X: (4096, 89, 128) f32;  Y: (4096, 66, 128) f32;  out: (4096, 66, 128) f32.
// Each of the 4 waves independently reduces the pressure row (512 B, cache-hot)
// and computes the 3 per-n coefficients in all lanes -> no LDS, no barrier.
// Y loads and out stores are nontemporal (touched once) to keep X in cache.

#define N_BATCH   4096
#define PI_F      3.14159265358979323846f
#define LN2_F     0.6931471805599453f

typedef float f32x4 __attribute__((ext_vector_type(4)));
typedef float f32x2 __attribute__((ext_vector_type(2)));

__global__ void __launch_bounds__(256) blackoil_fused(const float* __restrict__ X,
                                                      const float* __restrict__ Y,
                                                      float* __restrict__ out) {
    const int n = blockIdx.x;
    const int w = threadIdx.x >> 6;        // wave 0..3
    const int l = threadIdx.x & 63;        // lane

    const float* xb = X   + (size_t)n * (89 * 128);
    const float* yb = Y   + (size_t)n * (66 * 128);
    float*       ob = out + (size_t)n * (66 * 128);

    // ---- per-wave pressure mean (butterfly: all lanes get the sum) ----
    f32x2 pv = *reinterpret_cast<const f32x2*>(xb + 22 * 128 + l * 2);
    float sum = pv.x + pv.y;
    #pragma unroll
    for (int off = 1; off < 64; off <<= 1)
        sum += __shfl_xor(sum, off, 64);

    const float p  = sum * (1.0f / 128.0f);
    const float dd = p - 100.0f;                  // drawdown (negative)
    const bool  lt = (p < 0.5f);                  // p < P_BUB
    const float dp = lt ? (0.1f - p) : -0.4f;     // calc_dp
    const float bg = expf(-0.0017f * dp);         // calc_bg
    const float e1 = -8e-5f * dp;
    const float e2 = -1e-5f * (lt ? 0.0f : (p - 0.5f));
    const float bo = expf(-(e1 + e2));            // calc_bo
    const float mug = 3e-10f * p * p + 1e-6f * p + 0.0133f;
    const float add = fabsf(dd) * (2.0f * PI_F * 100.0f / LN2_F);
    const float cx = add / (2.5f * bo);           // oil
    const float cy = add;                         // water (UW*BW = 1)
    const float cz = add / (mug * bg);            // gas

    // ---- streaming elementwise over this n's 22x128 region ----
    const float inv_denom = 1.0f / 0.7f;          // 1/(1-SWI-SOR)
    const float scale     = 1e-10f / (float)N_BATCH;

    const f32x4* x4 = reinterpret_cast<const f32x4*>(xb);
    const f32x4* y4 = reinterpret_cast<const f32x4*>(yb);
    f32x4*       o4 = reinterpret_cast<f32x4*>(ob);

    // f32x4-region offsets: perm @0, Sg @1440, Sw @2144 (X);
    // oil @0, water @704, gas @1408 (Y, out). 704 f32x4-triplets per n.
    auto process = [&](int idx) {
        const f32x4 perm = x4[idx];
        const f32x4 sg   = x4[1440 + idx];
        const f32x4 sw   = x4[2144 + idx];
        const f32x4 r_o  = __builtin_nontemporal_load(&y4[idx]);
        const f32x4 r_w  = __builtin_nontemporal_load(&y4[704 + idx]);
        const f32x4 r_g  = __builtin_nontemporal_load(&y4[1408 + idx]);

        f32x4 oo, ow, og;
        #pragma unroll
        for (int j = 0; j < 4; ++j) {
            const float swn = (sw[j] - 0.1f) * inv_denom;
            const float sgn = sg[j] * inv_denom;
            const float krw = 0.3f * swn * swn;
            const float aa  = 1.0f - swn;
            const float bb  = 1.0f - sgn;
            const float kro = 0.9f * (aa * aa) * (bb * bb);
            const float krg = 0.8f * sgn * sgn;
            const float pk  = perm[j];
            oo[j] = (fabsf(cx * pk * kro) - r_o[j]) * scale;
            ow[j] = (fabsf(cy * pk * krw) - r_w[j]) * scale;
            og[j] = (fabsf(cz * pk * krg) - r_g[j]) * scale;
        }
        __builtin_nontemporal_store(oo, &o4[idx]);
        __builtin_nontemporal_store(ow, &o4[704 + idx]);
        __builtin_nontemporal_store(og, &o4[1408 + idx]);
    };

    // wave-uniform split: idx = 256k + 64w + l; k=0,1 for all waves, k=2 for w<3
    process(64 * w + l);
    process(256 + 64 * w + l);
    if (w < 3)
        process(512 + 64 * w + l);
}

extern "C" void kernel_launch(void* const* d_in, const int* in_sizes, int n_in,
                              void* d_out, int out_size, void* d_ws, size_t ws_size,
                              hipStream_t stream) {
    const float* X = (const float*)d_in[0];
    const float* Y = (const float*)d_in[1];
    float* out = (float*)d_out;
    blackoil_fused<<<N_BATCH, 256, 0, stream>>>(X, Y, out);
}